// Round 6
// baseline (123.115 us; speedup 1.0000x reference)
//
#include <hip/hip_runtime.h>
#include <math.h>

#define BN  32
#define H   80
#define W   80
#define HW  6400
#define KC  100
#define NCH 90
#define UW  640
#define UHW 409600   // 640*640

static constexpr size_t OUT_MNT   = 0;
static constexpr size_t OUT_KEEP  = (size_t)BN * KC * 4;          // 12800
static constexpr size_t OUT_ENH   = OUT_KEEP + (size_t)BN * KC;   // 16000
static constexpr size_t OUT_CLEAN = OUT_ENH + (size_t)BN * UHW;   // 13123200
static constexpr size_t OUT_ORI   = OUT_CLEAN + (size_t)BN * UHW; // 26230400

#define PI_F 3.14159265358979323846
#define MM_BLOCKS 64     // minmax partial blocks per image
#define ORI_BLOCKS 800   // BN*HW/4/64
#define CAP 2048         // candidate buffer capacity

// ---------------- float <-> order-preserving uint ----------------
__device__ __forceinline__ unsigned enc_f(float f) {
    unsigned u = __float_as_uint(f);
    return (u & 0x80000000u) ? ~u : (u | 0x80000000u);
}
__device__ __forceinline__ float dec_f(unsigned k) {
    return (k & 0x80000000u) ? __uint_as_float(k ^ 0x80000000u) : __uint_as_float(~k);
}
__device__ __forceinline__ unsigned long long shflx(unsigned long long v, int off) {
    unsigned hi = (unsigned)__shfl_xor((int)(unsigned)(v >> 32), off);
    unsigned lo = (unsigned)__shfl_xor((int)(unsigned)(v & 0xffffffffull), off);
    return ((unsigned long long)hi << 32) | lo;
}

// ========== Kernel 1: fused cleaned-mask + exact per-batch top-K =============
// Selection: threshold-ladder count -> compact survivors -> exact all-pairs
// rank. count(score>T) >= 100 guarantees top-100 subset of {score>T} (exact
// under ties since rank uses full (value,index) keys). Fallbacks cover
// degenerate distributions (never taken for this input, provably correct).
__global__ __launch_bounds__(512) void k_topk(const float* __restrict__ seg,
                                              const float* __restrict__ mscore,
                                              float* __restrict__ cleaned_g,
                                              int* __restrict__ ws_idx,
                                              float* __restrict__ ws_val) {
    __shared__ float s_clean[HW];                       // 25.6 KB
    __shared__ unsigned long long s_buf[3200];          // 25.6 KB: s_h | s_cand+s_red
    __shared__ unsigned long long s_sel[KC];
    __shared__ unsigned s_rm[HW / 32];                  // fallback removal bitmap
    __shared__ int s_cnt[5];
    __shared__ int s_n;
    __shared__ float s_T;
    __shared__ int s_mode;

    const int b = blockIdx.x, tid = threadIdx.x;
    const int lane = tid & 63;
    float* s_h = (float*)s_buf;
    unsigned long long* s_cand = s_buf;                 // after blur, s_h is dead
    unsigned long long* s_red  = s_buf + CAP;           // 512 entries

    // ---- gaussian weights (identical math to reference) ----
    float g[5];
    {
        float s = 0.f;
        #pragma unroll
        for (int i = 0; i < 5; i++) {
            float c = (float)(i - 2);
            g[i] = expf(-(c * c) / 4.5f);
            s += g[i];
        }
        #pragma unroll
        for (int i = 0; i < 5; i++) g[i] /= s;
    }

    // ---- stage rounded seg ----
    for (int i = tid; i < HW; i += 512) s_clean[i] = rintf(seg[(size_t)b * HW + i]);
    __syncthreads();

    // ---- horizontal 1x5 (zero-pad W) ----
    for (int i = tid; i < HW; i += 512) {
        int h = i / W, w = i % W;
        float acc = 0.f;
        #pragma unroll
        for (int dx = -2; dx <= 2; dx++) {
            int ww = w + dx;
            if (ww >= 0 && ww < W) acc += s_clean[h * W + ww] * g[dx + 2];
        }
        s_h[i] = acc;
    }
    __syncthreads();

    // ---- vertical 5x1 (zero-pad H) + round ----
    float loc[13];
    #pragma unroll
    for (int j = 0; j < 13; j++) {
        int i = j * 512 + tid;
        if (i < HW) {
            int h = i / W, w = i % W;
            float acc = 0.f;
            #pragma unroll
            for (int dy = -2; dy <= 2; dy++) {
                int hh = h + dy;
                if (hh >= 0 && hh < H) acc += s_h[hh * W + w] * g[dy + 2];
            }
            loc[j] = rintf(acc);
        }
    }
    __syncthreads();   // all s_h reads done (s_buf reused below)
    #pragma unroll
    for (int j = 0; j < 13; j++) {
        int i = j * 512 + tid;
        if (i < HW) {
            s_clean[i] = loc[j];
            cleaned_g[(size_t)b * HW + i] = loc[j];
        }
    }
    if (tid < HW / 32) s_rm[tid] = 0u;
    if (tid < 5) s_cnt[tid] = 0;
    __syncthreads();

    // ---- scores in registers (static indexing only) ----
    float sc[13];
    #pragma unroll
    for (int j = 0; j < 13; j++) {
        int i = j * 512 + tid;
        sc[j] = (i < HW) ? mscore[(size_t)b * HW + i] * s_clean[i] : -1.0f;
    }

    // ---- threshold-ladder counts ----
    int c0 = 0, c1 = 0, c2 = 0, c3 = 0, c4 = 0;
    #pragma unroll
    for (int j = 0; j < 13; j++) {
        float v = sc[j];
        c0 += (v > 0.95f); c1 += (v > 0.9f); c2 += (v > 0.8f);
        c3 += (v > 0.5f);  c4 += (v > 0.0f);
    }
    #pragma unroll
    for (int off = 32; off > 0; off >>= 1) {
        c0 += __shfl_xor(c0, off); c1 += __shfl_xor(c1, off);
        c2 += __shfl_xor(c2, off); c3 += __shfl_xor(c3, off);
        c4 += __shfl_xor(c4, off);
    }
    if (lane == 0) {
        atomicAdd(&s_cnt[0], c0); atomicAdd(&s_cnt[1], c1);
        atomicAdd(&s_cnt[2], c2); atomicAdd(&s_cnt[3], c3);
        atomicAdd(&s_cnt[4], c4);
    }
    __syncthreads();

    if (tid == 0) {
        int n95 = s_cnt[0], n90 = s_cnt[1], n80 = s_cnt[2], n50 = s_cnt[3], n0 = s_cnt[4];
        int mode; float T = 0.f;
        if (n0 < KC)                          { mode = 1; }            // include zeros
        else if (n95 >= KC && n95 <= CAP)     { mode = 0; T = 0.95f; } // expected path
        else if (n90 >= KC && n90 <= CAP)     { mode = 0; T = 0.9f; }
        else if (n80 >= KC && n80 <= CAP)     { mode = 0; T = 0.8f; }
        else if (n50 >= KC && n50 <= CAP)     { mode = 0; T = 0.5f; }
        else if (n0 <= CAP)                   { mode = 0; T = 0.0f; }
        else                                  { mode = 2; }            // pathological
        s_mode = mode; s_T = T; s_n = 0;
    }
    __syncthreads();
    const int mode = s_mode;

    if (mode != 2) {
        const float T = s_T;
        #pragma unroll
        for (int j = 0; j < 13; j++) {
            int i = j * 512 + tid;
            bool take = (mode == 0) ? (sc[j] > T)
                                    : (sc[j] > 0.f || (i < 256 && sc[j] == 0.0f));
            if (take) {
                int pos = atomicAdd(&s_n, 1);
                s_cand[pos] = ((unsigned long long)enc_f(sc[j]) << 32) | (unsigned)(HW - i);
            }
        }
        __syncthreads();
        const int n = s_n;   // in [100, CAP] by construction
        // exact rank: keys distinct -> ranks 0..n-1 are a permutation
        for (int c = tid; c < n; c += 512) {
            unsigned long long kk = s_cand[c];
            int rank = 0;
            for (int m = 0; m < n; m++) rank += (s_cand[m] > kk) ? 1 : 0;
            if (rank < KC) s_sel[rank] = kk;
        }
        __syncthreads();
    } else {
        // fallback: 100 iterative exact extractions (never taken for sane input)
        for (int k = 0; k < KC; k++) {
            unsigned long long lmax = 0ull;
            #pragma unroll
            for (int j = 0; j < 13; j++) {
                int i = j * 512 + tid;
                if (i < HW && sc[j] >= 0.f && !((s_rm[i >> 5] >> (i & 31)) & 1u)) {
                    unsigned long long kk =
                        ((unsigned long long)enc_f(sc[j]) << 32) | (unsigned)(HW - i);
                    if (kk > lmax) lmax = kk;
                }
            }
            s_red[tid] = lmax;
            __syncthreads();
            for (int off = 256; off > 0; off >>= 1) {
                if (tid < off) {
                    unsigned long long o = s_red[tid + off];
                    if (o > s_red[tid]) s_red[tid] = o;
                }
                __syncthreads();
            }
            if (tid == 0) {
                unsigned long long wkey = s_red[0];
                s_sel[k] = wkey;
                int wi = HW - (int)(wkey & 0xffffffffull);
                s_rm[wi >> 5] |= 1u << (wi & 31);
            }
            __syncthreads();
        }
    }

    if (tid < KC) {
        unsigned long long e = s_sel[tid];
        ws_idx[(size_t)b * KC + tid] = HW - (int)(e & 0xffffffffull);
        ws_val[(size_t)b * KC + tid] = dec_f((unsigned)(e >> 32));
    }
}

// ========== Kernel 2: fused orientation-argmax + minmax partials =============
__global__ __launch_bounds__(256) void k_pass1(const float* __restrict__ ori,
                                               const float* __restrict__ enh,
                                               const float* __restrict__ cleaned,
                                               float* __restrict__ ori_idx,
                                               float* __restrict__ pmin,
                                               float* __restrict__ pmax) {
    __shared__ float4 s_bv[256];
    __shared__ float4 s_bj[256];
    __shared__ float smin[4], smax[4];

    const int bx = blockIdx.x, tid = threadIdx.x;

    if (bx < ORI_BLOCKS) {
        // ---- orientation argmax: 64 float4-pixels x 4 channel-groups ----
        const int grp = tid >> 6, ln = tid & 63;
        const int p4 = bx * 64 + ln;                 // < BN*HW/4
        const int b = p4 / (HW / 4), pp = p4 % (HW / 4);
        const float4* o = (const float4*)(ori + (size_t)b * NCH * HW) + pp;
        const int cs = (grp * NCH) >> 2, ce = ((grp + 1) * NCH) >> 2;

        float4 bv = o[(size_t)cs * (HW / 4)];
        float4 bj = make_float4((float)cs, (float)cs, (float)cs, (float)cs);
        for (int j = cs + 1; j < ce; j++) {
            float4 v = o[(size_t)j * (HW / 4)];
            if (v.x > bv.x) { bv.x = v.x; bj.x = (float)j; }
            if (v.y > bv.y) { bv.y = v.y; bj.y = (float)j; }
            if (v.z > bv.z) { bv.z = v.z; bj.z = (float)j; }
            if (v.w > bv.w) { bv.w = v.w; bj.w = (float)j; }
        }
        s_bv[tid] = bv; s_bj[tid] = bj;
        __syncthreads();
        if (grp == 0) {
            #pragma unroll
            for (int g = 1; g < 4; g++) {
                float4 v = s_bv[g * 64 + ln], jx = s_bj[g * 64 + ln];
                if (v.x > bv.x) { bv.x = v.x; bj.x = jx.x; }
                if (v.y > bv.y) { bv.y = v.y; bj.y = jx.y; }
                if (v.z > bv.z) { bv.z = v.z; bj.z = jx.z; }
                if (v.w > bv.w) { bv.w = v.w; bj.w = jx.w; }
            }
            ((float4*)ori_idx)[p4] = bj;
        }
    } else {
        // ---- per-image min/max partials (no atomics) ----
        const int mb = bx - ORI_BLOCKS;              // [0, BN*MM_BLOCKS)
        const int b = mb >> 6, chunk = mb & 63;
        const float4* e4 = (const float4*)(enh + (size_t)b * UHW);
        const float* cb = cleaned + (size_t)b * HW;

        float vmin = INFINITY, vmax = -INFINITY;
        for (int i = chunk * 256 + tid; i < UHW / 4; i += MM_BLOCKS * 256) {
            float4 v = e4[i];
            int p = i * 4;
            int Y = p / UW, X = p % UW;              // 4-group stays in one x8 cell
            float c = cb[(Y >> 3) * W + (X >> 3)];
            float a = v.x * c, bb = v.y * c, cc = v.z * c, dd = v.w * c;
            vmin = fminf(vmin, fminf(fminf(a, bb), fminf(cc, dd)));
            vmax = fmaxf(vmax, fmaxf(fmaxf(a, bb), fmaxf(cc, dd)));
        }
        #pragma unroll
        for (int off = 32; off > 0; off >>= 1) {
            vmin = fminf(vmin, __shfl_xor(vmin, off));
            vmax = fmaxf(vmax, __shfl_xor(vmax, off));
        }
        int wave = tid >> 6, lane = tid & 63;
        if (lane == 0) { smin[wave] = vmin; smax[wave] = vmax; }
        __syncthreads();
        if (tid == 0) {
            float m0 = fminf(fminf(smin[0], smin[1]), fminf(smin[2], smin[3]));
            float m1 = fmaxf(fmaxf(smax[0], smax[1]), fmaxf(smax[2], smax[3]));
            pmin[b * MM_BLOCKS + chunk] = m0;
            pmax[b * MM_BLOCKS + chunk] = m1;
        }
    }
}

// ========== Kernel 3: one wave per candidate: channel argmax gather ==========
__global__ __launch_bounds__(256) void k_gather(const float* __restrict__ mori,
                                                const float* __restrict__ mxo,
                                                const float* __restrict__ myo,
                                                const int* __restrict__ ws_idx,
                                                const float* __restrict__ ws_val,
                                                float* __restrict__ out) {
    int wid = blockIdx.x * 4 + (threadIdx.x >> 6);
    int lane = threadIdx.x & 63;
    int b = wid / KC, k = wid % KC;
    int idx = ws_idx[(size_t)b * KC + k];

    const float* pm = mori + (size_t)b * NCH * HW + idx;
    unsigned long long kk =
        ((unsigned long long)enc_f(pm[(size_t)lane * HW]) << 32) | (unsigned)(127 - lane);
    if (lane < NCH - 64) {
        unsigned long long k1 =
            ((unsigned long long)enc_f(pm[(size_t)(64 + lane) * HW]) << 32) | (unsigned)(127 - (64 + lane));
        if (k1 > kk) kk = k1;
    }
    unsigned long long kx = 0ull, ky = 0ull;
    if (lane >= 32 && lane < 40)
        kx = ((unsigned long long)enc_f(mxo[((size_t)b * 8 + (lane - 32)) * HW + idx]) << 32)
             | (unsigned)(15 - (lane - 32));
    if (lane >= 40 && lane < 48)
        ky = ((unsigned long long)enc_f(myo[((size_t)b * 8 + (lane - 40)) * HW + idx]) << 32)
             | (unsigned)(15 - (lane - 40));

    #pragma unroll
    for (int off = 32; off > 0; off >>= 1) {
        unsigned long long o;
        o = shflx(kk, off); if (o > kk) kk = o;
        o = shflx(kx, off); if (o > kx) kx = o;
        o = shflx(ky, off); if (o > ky) ky = o;
    }

    if (lane == 0) {
        int ch = 127 - (int)(kk & 0xffffffffull);
        int xo = 15  - (int)(kx & 0xffffffffull);
        int yo = 15  - (int)(ky & 0xffffffffull);
        int r = idx / W, c = idx % W;
        float4 m;
        m.x = (float)c * 8.0f + (float)xo;
        m.y = (float)r * 8.0f + (float)yo;
        m.z = ((float)ch * 2.0f - 89.0f) * (float)(PI_F / 180.0);
        m.w = ws_val[(size_t)b * KC + k];
        ((float4*)(out + OUT_MNT))[(size_t)b * KC + k] = m;
    }
}

// ========== Kernel 4: fused sequential-NMS (blocks 0-31) + minmax-final ======
__global__ __launch_bounds__(64) void k_combo(const float* __restrict__ pmin,
                                              const float* __restrict__ pmax,
                                              float* __restrict__ mm,
                                              float* __restrict__ out) {
    const int bx = blockIdx.x, l = threadIdx.x;
    if (bx < BN) {
        const int b = bx;
        const float4* mnt = (const float4*)(out + OUT_MNT) + (size_t)b * KC;
        float4 m0 = mnt[l];
        bool has1 = (l + 64) < KC;
        float4 m1 = has1 ? mnt[l + 64] : make_float4(0.f, 0.f, 0.f, -1.f);
        int keep0 = (m0.w > 0.1f) ? 1 : 0;
        int keep1 = (has1 && m1.w > 0.1f) ? 1 : 0;

        for (int i = 0; i < KC; i++) {
            bool hi = i >= 64;
            int src = i & 63;
            float xi = __shfl(hi ? m1.x : m0.x, src);
            float yi = __shfl(hi ? m1.y : m0.y, src);
            float ai = __shfl(hi ? m1.z : m0.z, src);
            int   ki = __shfl(hi ? keep1 : keep0, src);
            if (ki) {
                if (keep0 && l > i) {
                    float dx = xi - m0.x, dy = yi - m0.y;
                    float dist = sqrtf(dx * dx + dy * dy);
                    float ad = fabsf(ai - m0.z);
                    float am = fminf(ad, (float)(2.0 * PI_F) - ad);
                    if (dist < 16.0f && am < (float)(PI_F / 6.0)) keep0 = 0;
                }
                if (keep1 && (l + 64) > i) {
                    float dx = xi - m1.x, dy = yi - m1.y;
                    float dist = sqrtf(dx * dx + dy * dy);
                    float ad = fabsf(ai - m1.z);
                    float am = fminf(ad, (float)(2.0 * PI_F) - ad);
                    if (dist < 16.0f && am < (float)(PI_F / 6.0)) keep1 = 0;
                }
            }
        }
        out[OUT_KEEP + (size_t)b * KC + l] = (float)keep0;
        if (has1) out[OUT_KEEP + (size_t)b * KC + 64 + l] = (float)keep1;
    } else {
        const int b = bx - BN;
        float vmin = pmin[b * MM_BLOCKS + l];
        float vmax = pmax[b * MM_BLOCKS + l];
        #pragma unroll
        for (int off = 32; off > 0; off >>= 1) {
            vmin = fminf(vmin, __shfl_xor(vmin, off));
            vmax = fmaxf(vmax, __shfl_xor(vmax, off));
        }
        if (l == 0) { mm[2 * b] = vmin; mm[2 * b + 1] = vmax; }
    }
}

// ========== Kernel 5: fused upsample + normalize + 3 outputs (float4) ========
__global__ __launch_bounds__(256) void k_final(const float* __restrict__ enh,
                                               const float* __restrict__ cleaned,
                                               const float* __restrict__ ori_idx,
                                               const float* __restrict__ mm,
                                               float* __restrict__ out) {
    int t4 = blockIdx.x * 256 + threadIdx.x;          // BN*UHW/4 threads
    int b = t4 / (UHW / 4), p4 = t4 % (UHW / 4);
    int p = p4 * 4;
    int Y = p / UW, X = p % UW;
    int cidx = b * HW + (Y >> 3) * W + (X >> 3);
    float c  = cleaned[cidx];
    float oi = ori_idx[cidx];
    float emin = mm[2 * b];
    float emax = mm[2 * b + 1];
    float inv = 255.0f / (emax - emin + 1e-8f);

    float4 e = ((const float4*)enh)[t4];
    float4 ev;
    ev.x = (e.x * c - emin) * inv;
    ev.y = (e.y * c - emin) * inv;
    ev.z = (e.z * c - emin) * inv;
    ev.w = (e.w * c - emin) * inv;

    float cv = c * 255.0f;
    float ov = (oi * 2.0f - 89.0f) * (float)(PI_F / 180.0) * c;

    ((float4*)(out + OUT_ENH))[t4]   = ev;
    ((float4*)(out + OUT_CLEAN))[t4] = make_float4(cv, cv, cv, cv);
    ((float4*)(out + OUT_ORI))[t4]   = make_float4(ov, ov, ov, ov);
}

extern "C" void kernel_launch(void* const* d_in, const int* in_sizes, int n_in,
                              void* d_out, int out_size, void* d_ws, size_t ws_size,
                              hipStream_t stream) {
    const float* seg    = (const float*)d_in[0];
    const float* mscore = (const float*)d_in[1];
    const float* mori   = (const float*)d_in[2];
    const float* mxo    = (const float*)d_in[3];
    const float* myo    = (const float*)d_in[4];
    const float* ori    = (const float*)d_in[5];
    const float* enh    = (const float*)d_in[6];
    float* out = (float*)d_out;

    // workspace layout
    float* cleaned = (float*)d_ws;                         // BN*HW
    float* ori_idx = cleaned + (size_t)BN * HW;            // BN*HW
    float* pmin    = ori_idx + (size_t)BN * HW;            // BN*MM_BLOCKS
    float* pmax    = pmin + (size_t)BN * MM_BLOCKS;        // BN*MM_BLOCKS
    float* mm      = pmax + (size_t)BN * MM_BLOCKS;        // 2*BN
    int*   ws_idx  = (int*)(mm + 2 * BN);                  // BN*KC
    float* ws_val  = (float*)(ws_idx + (size_t)BN * KC);   // BN*KC

    const int nBig4 = (BN * UHW / 4) / 256;                // 12800

    k_topk<<<BN, 512, 0, stream>>>(seg, mscore, cleaned, ws_idx, ws_val);
    k_pass1<<<ORI_BLOCKS + BN * MM_BLOCKS, 256, 0, stream>>>(ori, enh, cleaned,
                                                             ori_idx, pmin, pmax);
    k_gather<<<(BN * KC) / 4, 256, 0, stream>>>(mori, mxo, myo, ws_idx, ws_val, out);
    k_combo<<<2 * BN, 64, 0, stream>>>(pmin, pmax, mm, out);
    k_final<<<nBig4, 256, 0, stream>>>(enh, cleaned, ori_idx, mm, out);
}

// Round 7
// 122.366 us; speedup vs baseline: 1.0061x; 1.0061x over previous
//
#include <hip/hip_runtime.h>
#include <math.h>

#define BN  32
#define H   80
#define W   80
#define HW  6400
#define KC  100
#define NCH 90
#define UW  640
#define UHW 409600   // 640*640

static constexpr size_t OUT_MNT   = 0;
static constexpr size_t OUT_KEEP  = (size_t)BN * KC * 4;          // 12800
static constexpr size_t OUT_ENH   = OUT_KEEP + (size_t)BN * KC;   // 16000
static constexpr size_t OUT_CLEAN = OUT_ENH + (size_t)BN * UHW;   // 13123200
static constexpr size_t OUT_ORI   = OUT_CLEAN + (size_t)BN * UHW; // 26230400

#define PI_F 3.14159265358979323846
#define MM_BLOCKS 64     // minmax partial blocks per image
#define ORI_BLOCKS 800   // BN*HW/4/64
#define CAP 2048         // candidate buffer capacity

// ---------------- float <-> order-preserving uint ----------------
__device__ __forceinline__ unsigned enc_f(float f) {
    unsigned u = __float_as_uint(f);
    return (u & 0x80000000u) ? ~u : (u | 0x80000000u);
}
__device__ __forceinline__ float dec_f(unsigned k) {
    return (k & 0x80000000u) ? __uint_as_float(k ^ 0x80000000u) : __uint_as_float(~k);
}
__device__ __forceinline__ unsigned long long shflx(unsigned long long v, int off) {
    unsigned hi = (unsigned)__shfl_xor((int)(unsigned)(v >> 32), off);
    unsigned lo = (unsigned)__shfl_xor((int)(unsigned)(v & 0xffffffffull), off);
    return ((unsigned long long)hi << 32) | lo;
}

// ========== Kernel 1: fused cleaned-mask + exact per-batch top-K =============
// Selection: threshold-ladder count -> compact survivors -> exact all-pairs
// rank. count(score>T) >= 100 guarantees top-100 subset of {score>T} (exact
// under ties since rank uses full (value,index) keys). Fallbacks cover
// degenerate distributions (never taken for this input, provably correct).
__global__ __launch_bounds__(512) void k_topk(const float* __restrict__ seg,
                                              const float* __restrict__ mscore,
                                              float* __restrict__ cleaned_g,
                                              int* __restrict__ ws_idx,
                                              float* __restrict__ ws_val) {
    __shared__ float s_clean[HW];                       // 25.6 KB
    __shared__ unsigned long long s_buf[3200];          // 25.6 KB: s_h | s_cand+s_red
    __shared__ unsigned long long s_sel[KC];
    __shared__ unsigned s_rm[HW / 32];                  // fallback removal bitmap
    __shared__ int s_cnt[5];
    __shared__ int s_n;
    __shared__ float s_T;
    __shared__ int s_mode;

    const int b = blockIdx.x, tid = threadIdx.x;
    const int lane = tid & 63;
    float* s_h = (float*)s_buf;
    unsigned long long* s_cand = s_buf;                 // after blur, s_h is dead
    unsigned long long* s_red  = s_buf + CAP;           // 512 entries

    // ---- gaussian weights (identical math to reference) ----
    float g[5];
    {
        float s = 0.f;
        #pragma unroll
        for (int i = 0; i < 5; i++) {
            float c = (float)(i - 2);
            g[i] = expf(-(c * c) / 4.5f);
            s += g[i];
        }
        #pragma unroll
        for (int i = 0; i < 5; i++) g[i] /= s;
    }

    // ---- stage rounded seg ----
    for (int i = tid; i < HW; i += 512) s_clean[i] = rintf(seg[(size_t)b * HW + i]);
    __syncthreads();

    // ---- horizontal 1x5 (zero-pad W) ----
    for (int i = tid; i < HW; i += 512) {
        int h = i / W, w = i % W;
        float acc = 0.f;
        #pragma unroll
        for (int dx = -2; dx <= 2; dx++) {
            int ww = w + dx;
            if (ww >= 0 && ww < W) acc += s_clean[h * W + ww] * g[dx + 2];
        }
        s_h[i] = acc;
    }
    __syncthreads();

    // ---- vertical 5x1 (zero-pad H) + round ----
    float loc[13];
    #pragma unroll
    for (int j = 0; j < 13; j++) {
        int i = j * 512 + tid;
        if (i < HW) {
            int h = i / W, w = i % W;
            float acc = 0.f;
            #pragma unroll
            for (int dy = -2; dy <= 2; dy++) {
                int hh = h + dy;
                if (hh >= 0 && hh < H) acc += s_h[hh * W + w] * g[dy + 2];
            }
            loc[j] = rintf(acc);
        }
    }
    __syncthreads();   // all s_h reads done (s_buf reused below)
    #pragma unroll
    for (int j = 0; j < 13; j++) {
        int i = j * 512 + tid;
        if (i < HW) {
            s_clean[i] = loc[j];
            cleaned_g[(size_t)b * HW + i] = loc[j];
        }
    }
    if (tid < HW / 32) s_rm[tid] = 0u;
    if (tid < 5) s_cnt[tid] = 0;
    __syncthreads();

    // ---- scores in registers (static indexing only) ----
    float sc[13];
    #pragma unroll
    for (int j = 0; j < 13; j++) {
        int i = j * 512 + tid;
        sc[j] = (i < HW) ? mscore[(size_t)b * HW + i] * s_clean[i] : -1.0f;
    }

    // ---- threshold-ladder counts ----
    int c0 = 0, c1 = 0, c2 = 0, c3 = 0, c4 = 0;
    #pragma unroll
    for (int j = 0; j < 13; j++) {
        float v = sc[j];
        c0 += (v > 0.95f); c1 += (v > 0.9f); c2 += (v > 0.8f);
        c3 += (v > 0.5f);  c4 += (v > 0.0f);
    }
    #pragma unroll
    for (int off = 32; off > 0; off >>= 1) {
        c0 += __shfl_xor(c0, off); c1 += __shfl_xor(c1, off);
        c2 += __shfl_xor(c2, off); c3 += __shfl_xor(c3, off);
        c4 += __shfl_xor(c4, off);
    }
    if (lane == 0) {
        atomicAdd(&s_cnt[0], c0); atomicAdd(&s_cnt[1], c1);
        atomicAdd(&s_cnt[2], c2); atomicAdd(&s_cnt[3], c3);
        atomicAdd(&s_cnt[4], c4);
    }
    __syncthreads();

    if (tid == 0) {
        int n95 = s_cnt[0], n90 = s_cnt[1], n80 = s_cnt[2], n50 = s_cnt[3], n0 = s_cnt[4];
        int mode; float T = 0.f;
        if (n0 < KC)                          { mode = 1; }            // include zeros
        else if (n95 >= KC && n95 <= CAP)     { mode = 0; T = 0.95f; } // expected path
        else if (n90 >= KC && n90 <= CAP)     { mode = 0; T = 0.9f; }
        else if (n80 >= KC && n80 <= CAP)     { mode = 0; T = 0.8f; }
        else if (n50 >= KC && n50 <= CAP)     { mode = 0; T = 0.5f; }
        else if (n0 <= CAP)                   { mode = 0; T = 0.0f; }
        else                                  { mode = 2; }            // pathological
        s_mode = mode; s_T = T; s_n = 0;
    }
    __syncthreads();
    const int mode = s_mode;

    if (mode != 2) {
        const float T = s_T;
        #pragma unroll
        for (int j = 0; j < 13; j++) {
            int i = j * 512 + tid;
            bool take = (mode == 0) ? (sc[j] > T)
                                    : (sc[j] > 0.f || (i < 256 && sc[j] == 0.0f));
            if (take) {
                int pos = atomicAdd(&s_n, 1);
                s_cand[pos] = ((unsigned long long)enc_f(sc[j]) << 32) | (unsigned)(HW - i);
            }
        }
        __syncthreads();
        const int n = s_n;   // in [100, CAP] by construction
        // exact rank: keys distinct -> ranks 0..n-1 are a permutation
        for (int c = tid; c < n; c += 512) {
            unsigned long long kk = s_cand[c];
            int rank = 0;
            for (int m = 0; m < n; m++) rank += (s_cand[m] > kk) ? 1 : 0;
            if (rank < KC) s_sel[rank] = kk;
        }
        __syncthreads();
    } else {
        // fallback: 100 iterative exact extractions (never taken for sane input)
        for (int k = 0; k < KC; k++) {
            unsigned long long lmax = 0ull;
            #pragma unroll
            for (int j = 0; j < 13; j++) {
                int i = j * 512 + tid;
                if (i < HW && sc[j] >= 0.f && !((s_rm[i >> 5] >> (i & 31)) & 1u)) {
                    unsigned long long kk =
                        ((unsigned long long)enc_f(sc[j]) << 32) | (unsigned)(HW - i);
                    if (kk > lmax) lmax = kk;
                }
            }
            s_red[tid] = lmax;
            __syncthreads();
            for (int off = 256; off > 0; off >>= 1) {
                if (tid < off) {
                    unsigned long long o = s_red[tid + off];
                    if (o > s_red[tid]) s_red[tid] = o;
                }
                __syncthreads();
            }
            if (tid == 0) {
                unsigned long long wkey = s_red[0];
                s_sel[k] = wkey;
                int wi = HW - (int)(wkey & 0xffffffffull);
                s_rm[wi >> 5] |= 1u << (wi & 31);
            }
            __syncthreads();
        }
    }

    if (tid < KC) {
        unsigned long long e = s_sel[tid];
        ws_idx[(size_t)b * KC + tid] = HW - (int)(e & 0xffffffffull);
        ws_val[(size_t)b * KC + tid] = dec_f((unsigned)(e >> 32));
    }
}

// ========== Kernel 2: fused orientation-argmax + minmax partials =============
__global__ __launch_bounds__(256) void k_pass1(const float* __restrict__ ori,
                                               const float* __restrict__ enh,
                                               const float* __restrict__ cleaned,
                                               float* __restrict__ ori_idx,
                                               float* __restrict__ pmin,
                                               float* __restrict__ pmax) {
    __shared__ float4 s_bv[256];
    __shared__ float4 s_bj[256];
    __shared__ float smin[4], smax[4];

    const int bx = blockIdx.x, tid = threadIdx.x;

    if (bx < ORI_BLOCKS) {
        // ---- orientation argmax: 64 float4-pixels x 4 channel-groups ----
        const int grp = tid >> 6, ln = tid & 63;
        const int p4 = bx * 64 + ln;                 // < BN*HW/4
        const int b = p4 / (HW / 4), pp = p4 % (HW / 4);
        const float4* o = (const float4*)(ori + (size_t)b * NCH * HW) + pp;
        const int cs = (grp * NCH) >> 2, ce = ((grp + 1) * NCH) >> 2;

        float4 bv = o[(size_t)cs * (HW / 4)];
        float4 bj = make_float4((float)cs, (float)cs, (float)cs, (float)cs);
        for (int j = cs + 1; j < ce; j++) {
            float4 v = o[(size_t)j * (HW / 4)];
            if (v.x > bv.x) { bv.x = v.x; bj.x = (float)j; }
            if (v.y > bv.y) { bv.y = v.y; bj.y = (float)j; }
            if (v.z > bv.z) { bv.z = v.z; bj.z = (float)j; }
            if (v.w > bv.w) { bv.w = v.w; bj.w = (float)j; }
        }
        s_bv[tid] = bv; s_bj[tid] = bj;
        __syncthreads();
        if (grp == 0) {
            #pragma unroll
            for (int g = 1; g < 4; g++) {
                float4 v = s_bv[g * 64 + ln], jx = s_bj[g * 64 + ln];
                if (v.x > bv.x) { bv.x = v.x; bj.x = jx.x; }
                if (v.y > bv.y) { bv.y = v.y; bj.y = jx.y; }
                if (v.z > bv.z) { bv.z = v.z; bj.z = jx.z; }
                if (v.w > bv.w) { bv.w = v.w; bj.w = jx.w; }
            }
            ((float4*)ori_idx)[p4] = bj;
        }
    } else {
        // ---- per-image min/max partials (no atomics) ----
        const int mb = bx - ORI_BLOCKS;              // [0, BN*MM_BLOCKS)
        const int b = mb >> 6, chunk = mb & 63;
        const float4* e4 = (const float4*)(enh + (size_t)b * UHW);
        const float* cb = cleaned + (size_t)b * HW;

        float vmin = INFINITY, vmax = -INFINITY;
        for (int i = chunk * 256 + tid; i < UHW / 4; i += MM_BLOCKS * 256) {
            float4 v = e4[i];
            int p = i * 4;
            int Y = p / UW, X = p % UW;              // 4-group stays in one x8 cell
            float c = cb[(Y >> 3) * W + (X >> 3)];
            float a = v.x * c, bb = v.y * c, cc = v.z * c, dd = v.w * c;
            vmin = fminf(vmin, fminf(fminf(a, bb), fminf(cc, dd)));
            vmax = fmaxf(vmax, fmaxf(fmaxf(a, bb), fmaxf(cc, dd)));
        }
        #pragma unroll
        for (int off = 32; off > 0; off >>= 1) {
            vmin = fminf(vmin, __shfl_xor(vmin, off));
            vmax = fmaxf(vmax, __shfl_xor(vmax, off));
        }
        int wave = tid >> 6, lane = tid & 63;
        if (lane == 0) { smin[wave] = vmin; smax[wave] = vmax; }
        __syncthreads();
        if (tid == 0) {
            float m0 = fminf(fminf(smin[0], smin[1]), fminf(smin[2], smin[3]));
            float m1 = fmaxf(fmaxf(smax[0], smax[1]), fmaxf(smax[2], smax[3]));
            pmin[b * MM_BLOCKS + chunk] = m0;
            pmax[b * MM_BLOCKS + chunk] = m1;
        }
    }
}

// ========== Kernel 3: one wave per candidate: channel argmax gather ==========
__global__ __launch_bounds__(256) void k_gather(const float* __restrict__ mori,
                                                const float* __restrict__ mxo,
                                                const float* __restrict__ myo,
                                                const int* __restrict__ ws_idx,
                                                const float* __restrict__ ws_val,
                                                float* __restrict__ out) {
    int wid = blockIdx.x * 4 + (threadIdx.x >> 6);
    int lane = threadIdx.x & 63;
    int b = wid / KC, k = wid % KC;
    int idx = ws_idx[(size_t)b * KC + k];

    const float* pm = mori + (size_t)b * NCH * HW + idx;
    unsigned long long kk =
        ((unsigned long long)enc_f(pm[(size_t)lane * HW]) << 32) | (unsigned)(127 - lane);
    if (lane < NCH - 64) {
        unsigned long long k1 =
            ((unsigned long long)enc_f(pm[(size_t)(64 + lane) * HW]) << 32) | (unsigned)(127 - (64 + lane));
        if (k1 > kk) kk = k1;
    }
    unsigned long long kx = 0ull, ky = 0ull;
    if (lane >= 32 && lane < 40)
        kx = ((unsigned long long)enc_f(mxo[((size_t)b * 8 + (lane - 32)) * HW + idx]) << 32)
             | (unsigned)(15 - (lane - 32));
    if (lane >= 40 && lane < 48)
        ky = ((unsigned long long)enc_f(myo[((size_t)b * 8 + (lane - 40)) * HW + idx]) << 32)
             | (unsigned)(15 - (lane - 40));

    #pragma unroll
    for (int off = 32; off > 0; off >>= 1) {
        unsigned long long o;
        o = shflx(kk, off); if (o > kk) kk = o;
        o = shflx(kx, off); if (o > kx) kx = o;
        o = shflx(ky, off); if (o > ky) ky = o;
    }

    if (lane == 0) {
        int ch = 127 - (int)(kk & 0xffffffffull);
        int xo = 15  - (int)(kx & 0xffffffffull);
        int yo = 15  - (int)(ky & 0xffffffffull);
        int r = idx / W, c = idx % W;
        float4 m;
        m.x = (float)c * 8.0f + (float)xo;
        m.y = (float)r * 8.0f + (float)yo;
        m.z = ((float)ch * 2.0f - 89.0f) * (float)(PI_F / 180.0);
        m.w = ws_val[(size_t)b * KC + k];
        ((float4*)(out + OUT_MNT))[(size_t)b * KC + k] = m;
    }
}

// ========== Kernel 4: fused sequential-NMS (blocks 0-31) + minmax-final ======
__global__ __launch_bounds__(64) void k_combo(const float* __restrict__ pmin,
                                              const float* __restrict__ pmax,
                                              float* __restrict__ mm,
                                              float* __restrict__ out) {
    const int bx = blockIdx.x, l = threadIdx.x;
    if (bx < BN) {
        const int b = bx;
        const float4* mnt = (const float4*)(out + OUT_MNT) + (size_t)b * KC;
        float4 m0 = mnt[l];
        bool has1 = (l + 64) < KC;
        float4 m1 = has1 ? mnt[l + 64] : make_float4(0.f, 0.f, 0.f, -1.f);
        int keep0 = (m0.w > 0.1f) ? 1 : 0;
        int keep1 = (has1 && m1.w > 0.1f) ? 1 : 0;

        for (int i = 0; i < KC; i++) {
            bool hi = i >= 64;
            int src = i & 63;
            float xi = __shfl(hi ? m1.x : m0.x, src);
            float yi = __shfl(hi ? m1.y : m0.y, src);
            float ai = __shfl(hi ? m1.z : m0.z, src);
            int   ki = __shfl(hi ? keep1 : keep0, src);
            if (ki) {
                if (keep0 && l > i) {
                    float dx = xi - m0.x, dy = yi - m0.y;
                    float dist = sqrtf(dx * dx + dy * dy);
                    float ad = fabsf(ai - m0.z);
                    float am = fminf(ad, (float)(2.0 * PI_F) - ad);
                    if (dist < 16.0f && am < (float)(PI_F / 6.0)) keep0 = 0;
                }
                if (keep1 && (l + 64) > i) {
                    float dx = xi - m1.x, dy = yi - m1.y;
                    float dist = sqrtf(dx * dx + dy * dy);
                    float ad = fabsf(ai - m1.z);
                    float am = fminf(ad, (float)(2.0 * PI_F) - ad);
                    if (dist < 16.0f && am < (float)(PI_F / 6.0)) keep1 = 0;
                }
            }
        }
        out[OUT_KEEP + (size_t)b * KC + l] = (float)keep0;
        if (has1) out[OUT_KEEP + (size_t)b * KC + 64 + l] = (float)keep1;
    } else {
        const int b = bx - BN;
        float vmin = pmin[b * MM_BLOCKS + l];
        float vmax = pmax[b * MM_BLOCKS + l];
        #pragma unroll
        for (int off = 32; off > 0; off >>= 1) {
            vmin = fminf(vmin, __shfl_xor(vmin, off));
            vmax = fmaxf(vmax, __shfl_xor(vmax, off));
        }
        if (l == 0) { mm[2 * b] = vmin; mm[2 * b + 1] = vmax; }
    }
}

// ========== Kernel 5: fused upsample + normalize + 3 outputs (float4) ========
__global__ __launch_bounds__(256) void k_final(const float* __restrict__ enh,
                                               const float* __restrict__ cleaned,
                                               const float* __restrict__ ori_idx,
                                               const float* __restrict__ mm,
                                               float* __restrict__ out) {
    int t4 = blockIdx.x * 256 + threadIdx.x;          // BN*UHW/4 threads
    int b = t4 / (UHW / 4), p4 = t4 % (UHW / 4);
    int p = p4 * 4;
    int Y = p / UW, X = p % UW;
    int cidx = b * HW + (Y >> 3) * W + (X >> 3);
    float c  = cleaned[cidx];
    float oi = ori_idx[cidx];
    float emin = mm[2 * b];
    float emax = mm[2 * b + 1];
    float inv = 255.0f / (emax - emin + 1e-8f);

    float4 e = ((const float4*)enh)[t4];
    float4 ev;
    ev.x = (e.x * c - emin) * inv;
    ev.y = (e.y * c - emin) * inv;
    ev.z = (e.z * c - emin) * inv;
    ev.w = (e.w * c - emin) * inv;

    float cv = c * 255.0f;
    float ov = (oi * 2.0f - 89.0f) * (float)(PI_F / 180.0) * c;

    ((float4*)(out + OUT_ENH))[t4]   = ev;
    ((float4*)(out + OUT_CLEAN))[t4] = make_float4(cv, cv, cv, cv);
    ((float4*)(out + OUT_ORI))[t4]   = make_float4(ov, ov, ov, ov);
}

extern "C" void kernel_launch(void* const* d_in, const int* in_sizes, int n_in,
                              void* d_out, int out_size, void* d_ws, size_t ws_size,
                              hipStream_t stream) {
    const float* seg    = (const float*)d_in[0];
    const float* mscore = (const float*)d_in[1];
    const float* mori   = (const float*)d_in[2];
    const float* mxo    = (const float*)d_in[3];
    const float* myo    = (const float*)d_in[4];
    const float* ori    = (const float*)d_in[5];
    const float* enh    = (const float*)d_in[6];
    float* out = (float*)d_out;

    // workspace layout
    float* cleaned = (float*)d_ws;                         // BN*HW
    float* ori_idx = cleaned + (size_t)BN * HW;            // BN*HW
    float* pmin    = ori_idx + (size_t)BN * HW;            // BN*MM_BLOCKS
    float* pmax    = pmin + (size_t)BN * MM_BLOCKS;        // BN*MM_BLOCKS
    float* mm      = pmax + (size_t)BN * MM_BLOCKS;        // 2*BN
    int*   ws_idx  = (int*)(mm + 2 * BN);                  // BN*KC
    float* ws_val  = (float*)(ws_idx + (size_t)BN * KC);   // BN*KC

    const int nBig4 = (BN * UHW / 4) / 256;                // 12800

    k_topk<<<BN, 512, 0, stream>>>(seg, mscore, cleaned, ws_idx, ws_val);
    k_pass1<<<ORI_BLOCKS + BN * MM_BLOCKS, 256, 0, stream>>>(ori, enh, cleaned,
                                                             ori_idx, pmin, pmax);
    k_gather<<<(BN * KC) / 4, 256, 0, stream>>>(mori, mxo, myo, ws_idx, ws_val, out);
    k_combo<<<2 * BN, 64, 0, stream>>>(pmin, pmax, mm, out);
    k_final<<<nBig4, 256, 0, stream>>>(enh, cleaned, ori_idx, mm, out);
}

// Round 9
// 105.528 us; speedup vs baseline: 1.1667x; 1.1596x over previous
//
#include <hip/hip_runtime.h>
#include <math.h>

#define BN  32
#define H   80
#define W   80
#define HW  6400
#define KC  100
#define NCH 90
#define UW  640
#define UHW 409600   // 640*640

static constexpr size_t OUT_MNT   = 0;
static constexpr size_t OUT_KEEP  = (size_t)BN * KC * 4;          // 12800
static constexpr size_t OUT_ENH   = OUT_KEEP + (size_t)BN * KC;   // 16000
static constexpr size_t OUT_CLEAN = OUT_ENH + (size_t)BN * UHW;   // 13123200
static constexpr size_t OUT_ORI   = OUT_CLEAN + (size_t)BN * UHW; // 26230400

#define PI_F 3.14159265358979323846
#define MM_BLOCKS 64      // minmax partial chunks per image
#define ORI_MEGA  400     // ori blocks in k_mega (128 float4-pixels each)
#define CAP 2048          // candidate buffer capacity

typedef float vfloat4 __attribute__((ext_vector_type(4)));  // native vec for nt-stores

// ---------------- float <-> order-preserving uint ----------------
__device__ __forceinline__ unsigned enc_f(float f) {
    unsigned u = __float_as_uint(f);
    return (u & 0x80000000u) ? ~u : (u | 0x80000000u);
}
__device__ __forceinline__ float dec_f(unsigned k) {
    return (k & 0x80000000u) ? __uint_as_float(k ^ 0x80000000u) : __uint_as_float(~k);
}
__device__ __forceinline__ unsigned long long shflx(unsigned long long v, int off) {
    unsigned hi = (unsigned)__shfl_xor((int)(unsigned)(v >> 32), off);
    unsigned lo = (unsigned)__shfl_xor((int)(unsigned)(v & 0xffffffffull), off);
    return ((unsigned long long)hi << 32) | lo;
}

// ========== Kernel 1: cleaned mask (round -> separable blur -> round) ========
__global__ __launch_bounds__(512) void k_clean(const float* __restrict__ seg,
                                               float* __restrict__ cleaned_g) {
    __shared__ float s_in[HW];
    __shared__ float s_h[HW];
    const int b = blockIdx.x, tid = threadIdx.x;

    float g[5];
    {
        float s = 0.f;
        #pragma unroll
        for (int i = 0; i < 5; i++) {
            float c = (float)(i - 2);
            g[i] = expf(-(c * c) / 4.5f);
            s += g[i];
        }
        #pragma unroll
        for (int i = 0; i < 5; i++) g[i] /= s;
    }

    for (int i = tid; i < HW; i += 512) s_in[i] = rintf(seg[(size_t)b * HW + i]);
    __syncthreads();
    for (int i = tid; i < HW; i += 512) {
        int h = i / W, w = i % W;
        float acc = 0.f;
        #pragma unroll
        for (int dx = -2; dx <= 2; dx++) {
            int ww = w + dx;
            if (ww >= 0 && ww < W) acc += s_in[h * W + ww] * g[dx + 2];
        }
        s_h[i] = acc;
    }
    __syncthreads();
    for (int i = tid; i < HW; i += 512) {
        int h = i / W, w = i % W;
        float acc = 0.f;
        #pragma unroll
        for (int dy = -2; dy <= 2; dy++) {
            int hh = h + dy;
            if (hh >= 0 && hh < H) acc += s_h[hh * W + w] * g[dy + 2];
        }
        cleaned_g[(size_t)b * HW + i] = rintf(acc);
    }
}

// ========== Kernel 2: mega role-split ========================================
// blocks [0,32):                per-batch exact top-K (threshold-compact)
// blocks [32, 32+400):          orientation argmax (128 float4-pixels/block)
// blocks [432, 432+BN*64):      per-image min/max partials
__global__ __launch_bounds__(512) void k_mega(const float* __restrict__ mscore,
                                              const float* __restrict__ cleaned,
                                              const float* __restrict__ ori,
                                              const float* __restrict__ enh,
                                              float* __restrict__ ori_idx,
                                              float* __restrict__ pmin,
                                              float* __restrict__ pmax,
                                              int* __restrict__ ws_idx,
                                              float* __restrict__ ws_val) {
    __shared__ __align__(16) char um[20480];            // union buffer
    __shared__ unsigned long long s_sel[KC];
    __shared__ unsigned s_rm[HW / 32];
    __shared__ int s_cnt[5];
    __shared__ int s_n;
    __shared__ float s_T;
    __shared__ int s_mode;
    __shared__ float smin[8], smax[8];

    const int bx = blockIdx.x, tid = threadIdx.x;
    const int lane = tid & 63;

    if (bx < BN) {
        // ---------------- top-K selection ----------------
        unsigned long long* s_cand = (unsigned long long*)um;        // 2048
        unsigned long long* s_red  = (unsigned long long*)um + CAP;  // 512
        const int b = bx;

        if (tid < HW / 32) s_rm[tid] = 0u;
        if (tid < 5) s_cnt[tid] = 0;
        __syncthreads();

        float sc[13];
        #pragma unroll
        for (int j = 0; j < 13; j++) {
            int i = j * 512 + tid;
            sc[j] = (i < HW) ? mscore[(size_t)b * HW + i] * cleaned[(size_t)b * HW + i]
                             : -1.0f;
        }

        int c0 = 0, c1 = 0, c2 = 0, c3 = 0, c4 = 0;
        #pragma unroll
        for (int j = 0; j < 13; j++) {
            float v = sc[j];
            c0 += (v > 0.95f); c1 += (v > 0.9f); c2 += (v > 0.8f);
            c3 += (v > 0.5f);  c4 += (v > 0.0f);
        }
        #pragma unroll
        for (int off = 32; off > 0; off >>= 1) {
            c0 += __shfl_xor(c0, off); c1 += __shfl_xor(c1, off);
            c2 += __shfl_xor(c2, off); c3 += __shfl_xor(c3, off);
            c4 += __shfl_xor(c4, off);
        }
        if (lane == 0) {
            atomicAdd(&s_cnt[0], c0); atomicAdd(&s_cnt[1], c1);
            atomicAdd(&s_cnt[2], c2); atomicAdd(&s_cnt[3], c3);
            atomicAdd(&s_cnt[4], c4);
        }
        __syncthreads();

        if (tid == 0) {
            int n95 = s_cnt[0], n90 = s_cnt[1], n80 = s_cnt[2], n50 = s_cnt[3], n0 = s_cnt[4];
            int mode; float T = 0.f;
            if (n0 < KC)                      { mode = 1; }
            else if (n95 >= KC && n95 <= CAP) { mode = 0; T = 0.95f; }
            else if (n90 >= KC && n90 <= CAP) { mode = 0; T = 0.9f; }
            else if (n80 >= KC && n80 <= CAP) { mode = 0; T = 0.8f; }
            else if (n50 >= KC && n50 <= CAP) { mode = 0; T = 0.5f; }
            else if (n0 <= CAP)               { mode = 0; T = 0.0f; }
            else                              { mode = 2; }
            s_mode = mode; s_T = T; s_n = 0;
        }
        __syncthreads();
        const int mode = s_mode;

        if (mode != 2) {
            const float T = s_T;
            #pragma unroll
            for (int j = 0; j < 13; j++) {
                int i = j * 512 + tid;
                bool take = (mode == 0) ? (sc[j] > T)
                                        : (sc[j] > 0.f || (i < 256 && sc[j] == 0.0f));
                if (take) {
                    int pos = atomicAdd(&s_n, 1);
                    s_cand[pos] = ((unsigned long long)enc_f(sc[j]) << 32) | (unsigned)(HW - i);
                }
            }
            __syncthreads();
            const int n = s_n;
            for (int c = tid; c < n; c += 512) {
                unsigned long long kk = s_cand[c];
                int rank = 0;
                for (int m = 0; m < n; m++) rank += (s_cand[m] > kk) ? 1 : 0;
                if (rank < KC) s_sel[rank] = kk;
            }
            __syncthreads();
        } else {
            for (int k = 0; k < KC; k++) {
                unsigned long long lmax = 0ull;
                #pragma unroll
                for (int j = 0; j < 13; j++) {
                    int i = j * 512 + tid;
                    if (i < HW && sc[j] >= 0.f && !((s_rm[i >> 5] >> (i & 31)) & 1u)) {
                        unsigned long long kk =
                            ((unsigned long long)enc_f(sc[j]) << 32) | (unsigned)(HW - i);
                        if (kk > lmax) lmax = kk;
                    }
                }
                s_red[tid] = lmax;
                __syncthreads();
                for (int off = 256; off > 0; off >>= 1) {
                    if (tid < off) {
                        unsigned long long o = s_red[tid + off];
                        if (o > s_red[tid]) s_red[tid] = o;
                    }
                    __syncthreads();
                }
                if (tid == 0) {
                    unsigned long long wkey = s_red[0];
                    s_sel[k] = wkey;
                    int wi = HW - (int)(wkey & 0xffffffffull);
                    s_rm[wi >> 5] |= 1u << (wi & 31);
                }
                __syncthreads();
            }
        }

        if (tid < KC) {
            unsigned long long e = s_sel[tid];
            ws_idx[(size_t)b * KC + tid] = HW - (int)(e & 0xffffffffull);
            ws_val[(size_t)b * KC + tid] = dec_f((unsigned)(e >> 32));
        }
    } else if (bx < BN + ORI_MEGA) {
        // ---------------- orientation argmax ----------------
        float4* s_bv = (float4*)um;          // 512 float4 = 8KB
        float4* s_bj = (float4*)um + 512;    // 8KB
        const int grp = tid >> 7, ln = tid & 127;
        const int p4 = (bx - BN) * 128 + ln;             // < BN*HW/4
        const int b = p4 / (HW / 4), pp = p4 % (HW / 4);
        const float4* o = (const float4*)(ori + (size_t)b * NCH * HW) + pp;
        const int cs = (grp * NCH) >> 2, ce = ((grp + 1) * NCH) >> 2;

        float4 bv = o[(size_t)cs * (HW / 4)];
        float4 bj = make_float4((float)cs, (float)cs, (float)cs, (float)cs);
        for (int j = cs + 1; j < ce; j++) {
            float4 v = o[(size_t)j * (HW / 4)];
            if (v.x > bv.x) { bv.x = v.x; bj.x = (float)j; }
            if (v.y > bv.y) { bv.y = v.y; bj.y = (float)j; }
            if (v.z > bv.z) { bv.z = v.z; bj.z = (float)j; }
            if (v.w > bv.w) { bv.w = v.w; bj.w = (float)j; }
        }
        s_bv[tid] = bv; s_bj[tid] = bj;
        __syncthreads();
        if (grp == 0) {
            #pragma unroll
            for (int g = 1; g < 4; g++) {
                float4 v = s_bv[g * 128 + ln], jx = s_bj[g * 128 + ln];
                if (v.x > bv.x) { bv.x = v.x; bj.x = jx.x; }
                if (v.y > bv.y) { bv.y = v.y; bj.y = jx.y; }
                if (v.z > bv.z) { bv.z = v.z; bj.z = jx.z; }
                if (v.w > bv.w) { bv.w = v.w; bj.w = jx.w; }
            }
            ((float4*)ori_idx)[p4] = bj;
        }
    } else {
        // ---------------- min/max partials ----------------
        const int mb = bx - (BN + ORI_MEGA);             // [0, BN*MM_BLOCKS)
        const int b = mb >> 6, chunk = mb & 63;
        const float4* e4 = (const float4*)(enh + (size_t)b * UHW);
        const float* cb = cleaned + (size_t)b * HW;

        float vmin = INFINITY, vmax = -INFINITY;
        for (int i = chunk * 512 + tid; i < UHW / 4; i += MM_BLOCKS * 512) {
            float4 v = e4[i];
            int p = i * 4;
            int Y = p / UW, X = p % UW;                  // 4-group in one x8 cell
            float c = cb[(Y >> 3) * W + (X >> 3)];
            float a = v.x * c, bb = v.y * c, cc = v.z * c, dd = v.w * c;
            vmin = fminf(vmin, fminf(fminf(a, bb), fminf(cc, dd)));
            vmax = fmaxf(vmax, fmaxf(fmaxf(a, bb), fmaxf(cc, dd)));
        }
        #pragma unroll
        for (int off = 32; off > 0; off >>= 1) {
            vmin = fminf(vmin, __shfl_xor(vmin, off));
            vmax = fmaxf(vmax, __shfl_xor(vmax, off));
        }
        int wave = tid >> 6;
        if (lane == 0) { smin[wave] = vmin; smax[wave] = vmax; }
        __syncthreads();
        if (tid == 0) {
            float m0 = smin[0], m1 = smax[0];
            #pragma unroll
            for (int wv = 1; wv < 8; wv++) {
                m0 = fminf(m0, smin[wv]);
                m1 = fmaxf(m1, smax[wv]);
            }
            pmin[b * MM_BLOCKS + chunk] = m0;
            pmax[b * MM_BLOCKS + chunk] = m1;
        }
    }
}

// ========== Kernel 3: fused upsample + normalize + 3 outputs (float4) ========
__global__ __launch_bounds__(256) void k_final(const float* __restrict__ enh,
                                               const float* __restrict__ cleaned,
                                               const float* __restrict__ ori_idx,
                                               const float* __restrict__ pmin,
                                               const float* __restrict__ pmax,
                                               float* __restrict__ out) {
    __shared__ float s_emin, s_emax;
    const int b = blockIdx.x / 400;                   // 400 blocks per batch
    if (threadIdx.x < 64) {
        float vmin = pmin[b * MM_BLOCKS + threadIdx.x];
        float vmax = pmax[b * MM_BLOCKS + threadIdx.x];
        #pragma unroll
        for (int off = 32; off > 0; off >>= 1) {
            vmin = fminf(vmin, __shfl_xor(vmin, off));
            vmax = fmaxf(vmax, __shfl_xor(vmax, off));
        }
        if (threadIdx.x == 0) { s_emin = vmin; s_emax = vmax; }
    }
    __syncthreads();

    int t4 = blockIdx.x * 256 + threadIdx.x;          // BN*UHW/4 threads
    int p4 = t4 % (UHW / 4);
    int p = p4 * 4;
    int Y = p / UW, X = p % UW;
    int cidx = b * HW + (Y >> 3) * W + (X >> 3);
    float c  = cleaned[cidx];
    float oi = ori_idx[cidx];
    float emin = s_emin, emax = s_emax;
    float inv = 255.0f / (emax - emin + 1e-8f);

    float4 e = ((const float4*)enh)[t4];
    vfloat4 ev;
    ev.x = (e.x * c - emin) * inv;
    ev.y = (e.y * c - emin) * inv;
    ev.z = (e.z * c - emin) * inv;
    ev.w = (e.w * c - emin) * inv;

    float cv = c * 255.0f;
    float ov = (oi * 2.0f - 89.0f) * (float)(PI_F / 180.0) * c;
    vfloat4 cvv = {cv, cv, cv, cv};
    vfloat4 ovv = {ov, ov, ov, ov};

    __builtin_nontemporal_store(ev,  ((vfloat4*)(out + OUT_ENH))   + t4);
    __builtin_nontemporal_store(cvv, ((vfloat4*)(out + OUT_CLEAN)) + t4);
    __builtin_nontemporal_store(ovv, ((vfloat4*)(out + OUT_ORI))   + t4);
}

// ========== Kernel 4: one wave per candidate: channel argmax gather ==========
__global__ __launch_bounds__(256) void k_gather(const float* __restrict__ mori,
                                                const float* __restrict__ mxo,
                                                const float* __restrict__ myo,
                                                const int* __restrict__ ws_idx,
                                                const float* __restrict__ ws_val,
                                                float* __restrict__ out) {
    int wid = blockIdx.x * 4 + (threadIdx.x >> 6);
    int lane = threadIdx.x & 63;
    int b = wid / KC, k = wid % KC;
    int idx = ws_idx[(size_t)b * KC + k];

    const float* pm = mori + (size_t)b * NCH * HW + idx;
    unsigned long long kk =
        ((unsigned long long)enc_f(pm[(size_t)lane * HW]) << 32) | (unsigned)(127 - lane);
    if (lane < NCH - 64) {
        unsigned long long k1 =
            ((unsigned long long)enc_f(pm[(size_t)(64 + lane) * HW]) << 32) | (unsigned)(127 - (64 + lane));
        if (k1 > kk) kk = k1;
    }
    unsigned long long kx = 0ull, ky = 0ull;
    if (lane >= 32 && lane < 40)
        kx = ((unsigned long long)enc_f(mxo[((size_t)b * 8 + (lane - 32)) * HW + idx]) << 32)
             | (unsigned)(15 - (lane - 32));
    if (lane >= 40 && lane < 48)
        ky = ((unsigned long long)enc_f(myo[((size_t)b * 8 + (lane - 40)) * HW + idx]) << 32)
             | (unsigned)(15 - (lane - 40));

    #pragma unroll
    for (int off = 32; off > 0; off >>= 1) {
        unsigned long long o;
        o = shflx(kk, off); if (o > kk) kk = o;
        o = shflx(kx, off); if (o > kx) kx = o;
        o = shflx(ky, off); if (o > ky) ky = o;
    }

    if (lane == 0) {
        int ch = 127 - (int)(kk & 0xffffffffull);
        int xo = 15  - (int)(kx & 0xffffffffull);
        int yo = 15  - (int)(ky & 0xffffffffull);
        int r = idx / W, c = idx % W;
        float4 m;
        m.x = (float)c * 8.0f + (float)xo;
        m.y = (float)r * 8.0f + (float)yo;
        m.z = ((float)ch * 2.0f - 89.0f) * (float)(PI_F / 180.0);
        m.w = ws_val[(size_t)b * KC + k];
        ((float4*)(out + OUT_MNT))[(size_t)b * KC + k] = m;
    }
}

// ========== Kernel 5: sequential NMS, one wave per batch, registers ==========
__global__ __launch_bounds__(64) void k_nms(float* __restrict__ out) {
    const int b = blockIdx.x, l = threadIdx.x;
    const float4* mnt = (const float4*)(out + OUT_MNT) + (size_t)b * KC;
    float4 m0 = mnt[l];
    bool has1 = (l + 64) < KC;
    float4 m1 = has1 ? mnt[l + 64] : make_float4(0.f, 0.f, 0.f, -1.f);
    int keep0 = (m0.w > 0.1f) ? 1 : 0;
    int keep1 = (has1 && m1.w > 0.1f) ? 1 : 0;

    for (int i = 0; i < KC; i++) {
        bool hi = i >= 64;
        int src = i & 63;
        float xi = __shfl(hi ? m1.x : m0.x, src);
        float yi = __shfl(hi ? m1.y : m0.y, src);
        float ai = __shfl(hi ? m1.z : m0.z, src);
        int   ki = __shfl(hi ? keep1 : keep0, src);
        if (ki) {
            if (keep0 && l > i) {
                float dx = xi - m0.x, dy = yi - m0.y;
                float dist = sqrtf(dx * dx + dy * dy);
                float ad = fabsf(ai - m0.z);
                float am = fminf(ad, (float)(2.0 * PI_F) - ad);
                if (dist < 16.0f && am < (float)(PI_F / 6.0)) keep0 = 0;
            }
            if (keep1 && (l + 64) > i) {
                float dx = xi - m1.x, dy = yi - m1.y;
                float dist = sqrtf(dx * dx + dy * dy);
                float ad = fabsf(ai - m1.z);
                float am = fminf(ad, (float)(2.0 * PI_F) - ad);
                if (dist < 16.0f && am < (float)(PI_F / 6.0)) keep1 = 0;
            }
        }
    }
    out[OUT_KEEP + (size_t)b * KC + l] = (float)keep0;
    if (has1) out[OUT_KEEP + (size_t)b * KC + 64 + l] = (float)keep1;
}

extern "C" void kernel_launch(void* const* d_in, const int* in_sizes, int n_in,
                              void* d_out, int out_size, void* d_ws, size_t ws_size,
                              hipStream_t stream) {
    const float* seg    = (const float*)d_in[0];
    const float* mscore = (const float*)d_in[1];
    const float* mori   = (const float*)d_in[2];
    const float* mxo    = (const float*)d_in[3];
    const float* myo    = (const float*)d_in[4];
    const float* ori    = (const float*)d_in[5];
    const float* enh    = (const float*)d_in[6];
    float* out = (float*)d_out;

    // workspace layout
    float* cleaned = (float*)d_ws;                         // BN*HW
    float* ori_idx = cleaned + (size_t)BN * HW;            // BN*HW
    float* pmin    = ori_idx + (size_t)BN * HW;            // BN*MM_BLOCKS
    float* pmax    = pmin + (size_t)BN * MM_BLOCKS;        // BN*MM_BLOCKS
    int*   ws_idx  = (int*)(pmax + (size_t)BN * MM_BLOCKS);// BN*KC
    float* ws_val  = (float*)(ws_idx + (size_t)BN * KC);   // BN*KC

    const int nBig4 = (BN * UHW / 4) / 256;                // 12800
    const int nMega = BN + ORI_MEGA + BN * MM_BLOCKS;      // 2480

    k_clean<<<BN, 512, 0, stream>>>(seg, cleaned);
    k_mega<<<nMega, 512, 0, stream>>>(mscore, cleaned, ori, enh,
                                      ori_idx, pmin, pmax, ws_idx, ws_val);
    k_final<<<nBig4, 256, 0, stream>>>(enh, cleaned, ori_idx, pmin, pmax, out);
    k_gather<<<(BN * KC) / 4, 256, 0, stream>>>(mori, mxo, myo, ws_idx, ws_val, out);
    k_nms<<<BN, 64, 0, stream>>>(out);
}

// Round 11
// 95.149 us; speedup vs baseline: 1.2939x; 1.1091x over previous
//
#include <hip/hip_runtime.h>
#include <math.h>

#define BN  32
#define H   80
#define W   80
#define HW  6400
#define KC  100
#define NCH 90
#define UW  640
#define UHW 409600   // 640*640

static constexpr size_t OUT_MNT   = 0;
static constexpr size_t OUT_KEEP  = (size_t)BN * KC * 4;          // 12800
static constexpr size_t OUT_ENH   = OUT_KEEP + (size_t)BN * KC;   // 16000
static constexpr size_t OUT_CLEAN = OUT_ENH + (size_t)BN * UHW;   // 13123200
static constexpr size_t OUT_ORI   = OUT_CLEAN + (size_t)BN * UHW; // 26230400

#define PI_F 3.14159265358979323846
#define MM_BLOCKS 64      // minmax partial chunks per image
#define ORI_MEGA  400     // ori blocks in k_mega (128 float4-pixels each)
#define CAP 2048          // candidate buffer capacity
#define GAT_BLOCKS 800    // gather blocks in k_fg (4 candidates each)
#define FIN_BLOCKS 12800  // final-write blocks in k_fg

typedef float vfloat4 __attribute__((ext_vector_type(4)));  // native vec for nt-stores

// ---------------- float <-> order-preserving uint ----------------
__device__ __forceinline__ unsigned enc_f(float f) {
    unsigned u = __float_as_uint(f);
    return (u & 0x80000000u) ? ~u : (u | 0x80000000u);
}
__device__ __forceinline__ float dec_f(unsigned k) {
    return (k & 0x80000000u) ? __uint_as_float(k ^ 0x80000000u) : __uint_as_float(~k);
}
__device__ __forceinline__ unsigned long long shflx(unsigned long long v, int off) {
    unsigned hi = (unsigned)__shfl_xor((int)(unsigned)(v >> 32), off);
    unsigned lo = (unsigned)__shfl_xor((int)(unsigned)(v & 0xffffffffull), off);
    return ((unsigned long long)hi << 32) | lo;
}

// ========== Kernel 1: cleaned mask, band-parallel (320 blocks) ===============
// Each block: one 8-row band of one image. Stage 12 rows (band +/- 2, zero
// outside), horizontal blur in LDS, vertical blur for the 8 rows, round.
// Summation order identical to the R9-passing kernel; OOB terms add exact +0
// (all values non-negative, so no -0 hazards).
__global__ __launch_bounds__(512) void k_clean(const float* __restrict__ seg,
                                               float* __restrict__ cleaned_g) {
    __shared__ float s_in[12 * 80];
    __shared__ float s_h[12 * 80];
    const int blk = blockIdx.x;          // 0 .. BN*10-1
    const int b = blk / 10, band = blk % 10;
    const int r0 = band * 8 - 2;         // global row of local row 0
    const int tid = threadIdx.x;

    float g[5];
    {
        float s = 0.f;
        #pragma unroll
        for (int i = 0; i < 5; i++) {
            float c = (float)(i - 2);
            g[i] = expf(-(c * c) / 4.5f);
            s += g[i];
        }
        #pragma unroll
        for (int i = 0; i < 5; i++) g[i] /= s;
    }

    for (int i = tid; i < 12 * 80; i += 512) {
        int lr = i / 80, w = i % 80;
        int gr = r0 + lr;
        s_in[i] = (gr >= 0 && gr < H) ? rintf(seg[(size_t)b * HW + gr * W + w]) : 0.f;
    }
    __syncthreads();
    for (int i = tid; i < 12 * 80; i += 512) {
        int lr = i / 80, w = i % 80;
        float acc = 0.f;
        #pragma unroll
        for (int dx = -2; dx <= 2; dx++) {
            int ww = w + dx;
            if (ww >= 0 && ww < W) acc += s_in[lr * 80 + ww] * g[dx + 2];
        }
        s_h[i] = acc;
    }
    __syncthreads();
    for (int i = tid; i < 8 * 80; i += 512) {
        int k = i / 80, w = i % 80;
        float acc = 0.f;
        #pragma unroll
        for (int dy = 0; dy < 5; dy++) acc += s_h[(k + dy) * 80 + w] * g[dy];
        cleaned_g[(size_t)b * HW + (band * 8 + k) * W + w] = rintf(acc);
    }
}

// ========== Kernel 2: mega role-split ========================================
// blocks [0,32):                per-batch exact top-K (threshold-compact)
// blocks [32, 32+400):          orientation argmax (128 float4-pixels/block)
// blocks [432, 432+BN*64):      per-image min/max partials
__global__ __launch_bounds__(512) void k_mega(const float* __restrict__ mscore,
                                              const float* __restrict__ cleaned,
                                              const float* __restrict__ ori,
                                              const float* __restrict__ enh,
                                              float* __restrict__ ori_idx,
                                              float* __restrict__ pmin,
                                              float* __restrict__ pmax,
                                              int* __restrict__ ws_idx,
                                              float* __restrict__ ws_val) {
    __shared__ __align__(16) char um[20480];            // union buffer
    __shared__ unsigned long long s_sel[KC];
    __shared__ unsigned s_rm[HW / 32];
    __shared__ int s_cnt[5];
    __shared__ int s_n;
    __shared__ float s_T;
    __shared__ int s_mode;
    __shared__ float smin[8], smax[8];

    const int bx = blockIdx.x, tid = threadIdx.x;
    const int lane = tid & 63;

    if (bx < BN) {
        // ---------------- top-K selection ----------------
        unsigned long long* s_cand = (unsigned long long*)um;        // 2048
        unsigned long long* s_red  = (unsigned long long*)um + CAP;  // 512
        const int b = bx;

        if (tid < HW / 32) s_rm[tid] = 0u;
        if (tid < 5) s_cnt[tid] = 0;
        __syncthreads();

        float sc[13];
        #pragma unroll
        for (int j = 0; j < 13; j++) {
            int i = j * 512 + tid;
            sc[j] = (i < HW) ? mscore[(size_t)b * HW + i] * cleaned[(size_t)b * HW + i]
                             : -1.0f;
        }

        int c0 = 0, c1 = 0, c2 = 0, c3 = 0, c4 = 0;
        #pragma unroll
        for (int j = 0; j < 13; j++) {
            float v = sc[j];
            c0 += (v > 0.95f); c1 += (v > 0.9f); c2 += (v > 0.8f);
            c3 += (v > 0.5f);  c4 += (v > 0.0f);
        }
        #pragma unroll
        for (int off = 32; off > 0; off >>= 1) {
            c0 += __shfl_xor(c0, off); c1 += __shfl_xor(c1, off);
            c2 += __shfl_xor(c2, off); c3 += __shfl_xor(c3, off);
            c4 += __shfl_xor(c4, off);
        }
        if (lane == 0) {
            atomicAdd(&s_cnt[0], c0); atomicAdd(&s_cnt[1], c1);
            atomicAdd(&s_cnt[2], c2); atomicAdd(&s_cnt[3], c3);
            atomicAdd(&s_cnt[4], c4);
        }
        __syncthreads();

        if (tid == 0) {
            int n95 = s_cnt[0], n90 = s_cnt[1], n80 = s_cnt[2], n50 = s_cnt[3], n0 = s_cnt[4];
            int mode; float T = 0.f;
            if (n0 < KC)                      { mode = 1; }
            else if (n95 >= KC && n95 <= CAP) { mode = 0; T = 0.95f; }
            else if (n90 >= KC && n90 <= CAP) { mode = 0; T = 0.9f; }
            else if (n80 >= KC && n80 <= CAP) { mode = 0; T = 0.8f; }
            else if (n50 >= KC && n50 <= CAP) { mode = 0; T = 0.5f; }
            else if (n0 <= CAP)               { mode = 0; T = 0.0f; }
            else                              { mode = 2; }
            s_mode = mode; s_T = T; s_n = 0;
        }
        __syncthreads();
        const int mode = s_mode;

        if (mode != 2) {
            const float T = s_T;
            #pragma unroll
            for (int j = 0; j < 13; j++) {
                int i = j * 512 + tid;
                bool take = (mode == 0) ? (sc[j] > T)
                                        : (sc[j] > 0.f || (i < 256 && sc[j] == 0.0f));
                if (take) {
                    int pos = atomicAdd(&s_n, 1);
                    s_cand[pos] = ((unsigned long long)enc_f(sc[j]) << 32) | (unsigned)(HW - i);
                }
            }
            __syncthreads();
            const int n = s_n;
            for (int c = tid; c < n; c += 512) {
                unsigned long long kk = s_cand[c];
                int rank = 0;
                for (int m = 0; m < n; m++) rank += (s_cand[m] > kk) ? 1 : 0;
                if (rank < KC) s_sel[rank] = kk;
            }
            __syncthreads();
        } else {
            for (int k = 0; k < KC; k++) {
                unsigned long long lmax = 0ull;
                #pragma unroll
                for (int j = 0; j < 13; j++) {
                    int i = j * 512 + tid;
                    if (i < HW && sc[j] >= 0.f && !((s_rm[i >> 5] >> (i & 31)) & 1u)) {
                        unsigned long long kk =
                            ((unsigned long long)enc_f(sc[j]) << 32) | (unsigned)(HW - i);
                        if (kk > lmax) lmax = kk;
                    }
                }
                s_red[tid] = lmax;
                __syncthreads();
                for (int off = 256; off > 0; off >>= 1) {
                    if (tid < off) {
                        unsigned long long o = s_red[tid + off];
                        if (o > s_red[tid]) s_red[tid] = o;
                    }
                    __syncthreads();
                }
                if (tid == 0) {
                    unsigned long long wkey = s_red[0];
                    s_sel[k] = wkey;
                    int wi = HW - (int)(wkey & 0xffffffffull);
                    s_rm[wi >> 5] |= 1u << (wi & 31);
                }
                __syncthreads();
            }
        }

        if (tid < KC) {
            unsigned long long e = s_sel[tid];
            ws_idx[(size_t)b * KC + tid] = HW - (int)(e & 0xffffffffull);
            ws_val[(size_t)b * KC + tid] = dec_f((unsigned)(e >> 32));
        }
    } else if (bx < BN + ORI_MEGA) {
        // ---------------- orientation argmax ----------------
        float4* s_bv = (float4*)um;          // 512 float4 = 8KB
        float4* s_bj = (float4*)um + 512;    // 8KB
        const int grp = tid >> 7, ln = tid & 127;
        const int p4 = (bx - BN) * 128 + ln;             // < BN*HW/4
        const int b = p4 / (HW / 4), pp = p4 % (HW / 4);
        const float4* o = (const float4*)(ori + (size_t)b * NCH * HW) + pp;
        const int cs = (grp * NCH) >> 2, ce = ((grp + 1) * NCH) >> 2;

        float4 bv = o[(size_t)cs * (HW / 4)];
        float4 bj = make_float4((float)cs, (float)cs, (float)cs, (float)cs);
        for (int j = cs + 1; j < ce; j++) {
            float4 v = o[(size_t)j * (HW / 4)];
            if (v.x > bv.x) { bv.x = v.x; bj.x = (float)j; }
            if (v.y > bv.y) { bv.y = v.y; bj.y = (float)j; }
            if (v.z > bv.z) { bv.z = v.z; bj.z = (float)j; }
            if (v.w > bv.w) { bv.w = v.w; bj.w = (float)j; }
        }
        s_bv[tid] = bv; s_bj[tid] = bj;
        __syncthreads();
        if (grp == 0) {
            #pragma unroll
            for (int g = 1; g < 4; g++) {
                float4 v = s_bv[g * 128 + ln], jx = s_bj[g * 128 + ln];
                if (v.x > bv.x) { bv.x = v.x; bj.x = jx.x; }
                if (v.y > bv.y) { bv.y = v.y; bj.y = jx.y; }
                if (v.z > bv.z) { bv.z = v.z; bj.z = jx.z; }
                if (v.w > bv.w) { bv.w = v.w; bj.w = jx.w; }
            }
            ((float4*)ori_idx)[p4] = bj;
        }
    } else {
        // ---------------- min/max partials ----------------
        const int mb = bx - (BN + ORI_MEGA);             // [0, BN*MM_BLOCKS)
        const int b = mb >> 6, chunk = mb & 63;
        const float4* e4 = (const float4*)(enh + (size_t)b * UHW);
        const float* cb = cleaned + (size_t)b * HW;

        float vmin = INFINITY, vmax = -INFINITY;
        for (int i = chunk * 512 + tid; i < UHW / 4; i += MM_BLOCKS * 512) {
            float4 v = e4[i];
            int p = i * 4;
            int Y = p / UW, X = p % UW;                  // 4-group in one x8 cell
            float c = cb[(Y >> 3) * W + (X >> 3)];
            float a = v.x * c, bb = v.y * c, cc = v.z * c, dd = v.w * c;
            vmin = fminf(vmin, fminf(fminf(a, bb), fminf(cc, dd)));
            vmax = fmaxf(vmax, fmaxf(fmaxf(a, bb), fmaxf(cc, dd)));
        }
        #pragma unroll
        for (int off = 32; off > 0; off >>= 1) {
            vmin = fminf(vmin, __shfl_xor(vmin, off));
            vmax = fmaxf(vmax, __shfl_xor(vmax, off));
        }
        int wave = tid >> 6;
        if (lane == 0) { smin[wave] = vmin; smax[wave] = vmax; }
        __syncthreads();
        if (tid == 0) {
            float m0 = smin[0], m1 = smax[0];
            #pragma unroll
            for (int wv = 1; wv < 8; wv++) {
                m0 = fminf(m0, smin[wv]);
                m1 = fmaxf(m1, smax[wv]);
            }
            pmin[b * MM_BLOCKS + chunk] = m0;
            pmax[b * MM_BLOCKS + chunk] = m1;
        }
    }
}

// ========== Kernel 3: role-split gather (first 800) + final writes ===========
__global__ __launch_bounds__(256) void k_fg(const float* __restrict__ enh,
                                            const float* __restrict__ cleaned,
                                            const float* __restrict__ ori_idx,
                                            const float* __restrict__ pmin,
                                            const float* __restrict__ pmax,
                                            const float* __restrict__ mori,
                                            const float* __restrict__ mxo,
                                            const float* __restrict__ myo,
                                            const int* __restrict__ ws_idx,
                                            const float* __restrict__ ws_val,
                                            float* __restrict__ out) {
    const int bx = blockIdx.x, tid = threadIdx.x;

    if (bx < GAT_BLOCKS) {
        // ---------------- gather: one wave per candidate ----------------
        const int lane = tid & 63;
        const int wid = bx * 4 + (tid >> 6);
        const int b = wid / KC, k = wid % KC;
        const int idx = ws_idx[(size_t)b * KC + k];

        const float* pm = mori + (size_t)b * NCH * HW + idx;
        unsigned long long kk =
            ((unsigned long long)enc_f(pm[(size_t)lane * HW]) << 32) | (unsigned)(127 - lane);
        if (lane < NCH - 64) {
            unsigned long long k1 =
                ((unsigned long long)enc_f(pm[(size_t)(64 + lane) * HW]) << 32)
                | (unsigned)(127 - (64 + lane));
            if (k1 > kk) kk = k1;
        }
        unsigned long long kx = 0ull, ky = 0ull;
        if (lane >= 32 && lane < 40)
            kx = ((unsigned long long)enc_f(mxo[((size_t)b * 8 + (lane - 32)) * HW + idx]) << 32)
                 | (unsigned)(15 - (lane - 32));
        if (lane >= 40 && lane < 48)
            ky = ((unsigned long long)enc_f(myo[((size_t)b * 8 + (lane - 40)) * HW + idx]) << 32)
                 | (unsigned)(15 - (lane - 40));

        #pragma unroll
        for (int off = 32; off > 0; off >>= 1) {
            unsigned long long o;
            o = shflx(kk, off); if (o > kk) kk = o;
            o = shflx(kx, off); if (o > kx) kx = o;
            o = shflx(ky, off); if (o > ky) ky = o;
        }

        if (lane == 0) {
            int ch = 127 - (int)(kk & 0xffffffffull);
            int xo = 15  - (int)(kx & 0xffffffffull);
            int yo = 15  - (int)(ky & 0xffffffffull);
            int r = idx / W, c = idx % W;
            float4 m;
            m.x = (float)c * 8.0f + (float)xo;
            m.y = (float)r * 8.0f + (float)yo;
            m.z = ((float)ch * 2.0f - 89.0f) * (float)(PI_F / 180.0);
            m.w = ws_val[(size_t)b * KC + k];
            ((float4*)(out + OUT_MNT))[(size_t)b * KC + k] = m;
        }
    } else {
        // ---------------- final write: upsample + normalize + 3 outputs ------
        __shared__ float s_emin, s_emax;
        const int fb = bx - GAT_BLOCKS;               // [0, FIN_BLOCKS)
        const int b = fb / 400;                       // 400 blocks per batch
        if (tid < 64) {
            float vmin = pmin[b * MM_BLOCKS + tid];
            float vmax = pmax[b * MM_BLOCKS + tid];
            #pragma unroll
            for (int off = 32; off > 0; off >>= 1) {
                vmin = fminf(vmin, __shfl_xor(vmin, off));
                vmax = fmaxf(vmax, __shfl_xor(vmax, off));
            }
            if (tid == 0) { s_emin = vmin; s_emax = vmax; }
        }
        __syncthreads();

        int t4 = fb * 256 + tid;                      // BN*UHW/4 threads
        int p4 = t4 % (UHW / 4);
        int p = p4 * 4;
        int Y = p / UW, X = p % UW;
        int cidx = b * HW + (Y >> 3) * W + (X >> 3);
        float c  = cleaned[cidx];
        float oi = ori_idx[cidx];
        float emin = s_emin, emax = s_emax;
        float inv = 255.0f / (emax - emin + 1e-8f);

        float4 e = ((const float4*)enh)[t4];
        vfloat4 ev;
        ev.x = (e.x * c - emin) * inv;
        ev.y = (e.y * c - emin) * inv;
        ev.z = (e.z * c - emin) * inv;
        ev.w = (e.w * c - emin) * inv;

        float cv = c * 255.0f;
        float ov = (oi * 2.0f - 89.0f) * (float)(PI_F / 180.0) * c;
        vfloat4 cvv = {cv, cv, cv, cv};
        vfloat4 ovv = {ov, ov, ov, ov};

        __builtin_nontemporal_store(ev,  ((vfloat4*)(out + OUT_ENH))   + t4);
        __builtin_nontemporal_store(cvv, ((vfloat4*)(out + OUT_CLEAN)) + t4);
        __builtin_nontemporal_store(ovv, ((vfloat4*)(out + OUT_ORI))   + t4);
    }
}

// ========== Kernel 4: sequential NMS, one wave per batch, registers ==========
__global__ __launch_bounds__(64) void k_nms(float* __restrict__ out) {
    const int b = blockIdx.x, l = threadIdx.x;
    const float4* mnt = (const float4*)(out + OUT_MNT) + (size_t)b * KC;
    float4 m0 = mnt[l];
    bool has1 = (l + 64) < KC;
    float4 m1 = has1 ? mnt[l + 64] : make_float4(0.f, 0.f, 0.f, -1.f);
    int keep0 = (m0.w > 0.1f) ? 1 : 0;
    int keep1 = (has1 && m1.w > 0.1f) ? 1 : 0;

    for (int i = 0; i < KC; i++) {
        bool hi = i >= 64;
        int src = i & 63;
        float xi = __shfl(hi ? m1.x : m0.x, src);
        float yi = __shfl(hi ? m1.y : m0.y, src);
        float ai = __shfl(hi ? m1.z : m0.z, src);
        int   ki = __shfl(hi ? keep1 : keep0, src);
        if (ki) {
            if (keep0 && l > i) {
                float dx = xi - m0.x, dy = yi - m0.y;
                float dist = sqrtf(dx * dx + dy * dy);
                float ad = fabsf(ai - m0.z);
                float am = fminf(ad, (float)(2.0 * PI_F) - ad);
                if (dist < 16.0f && am < (float)(PI_F / 6.0)) keep0 = 0;
            }
            if (keep1 && (l + 64) > i) {
                float dx = xi - m1.x, dy = yi - m1.y;
                float dist = sqrtf(dx * dx + dy * dy);
                float ad = fabsf(ai - m1.z);
                float am = fminf(ad, (float)(2.0 * PI_F) - ad);
                if (dist < 16.0f && am < (float)(PI_F / 6.0)) keep1 = 0;
            }
        }
    }
    out[OUT_KEEP + (size_t)b * KC + l] = (float)keep0;
    if (has1) out[OUT_KEEP + (size_t)b * KC + 64 + l] = (float)keep1;
}

extern "C" void kernel_launch(void* const* d_in, const int* in_sizes, int n_in,
                              void* d_out, int out_size, void* d_ws, size_t ws_size,
                              hipStream_t stream) {
    const float* seg    = (const float*)d_in[0];
    const float* mscore = (const float*)d_in[1];
    const float* mori   = (const float*)d_in[2];
    const float* mxo    = (const float*)d_in[3];
    const float* myo    = (const float*)d_in[4];
    const float* ori    = (const float*)d_in[5];
    const float* enh    = (const float*)d_in[6];
    float* out = (float*)d_out;

    // workspace layout
    float* cleaned = (float*)d_ws;                         // BN*HW
    float* ori_idx = cleaned + (size_t)BN * HW;            // BN*HW
    float* pmin    = ori_idx + (size_t)BN * HW;            // BN*MM_BLOCKS
    float* pmax    = pmin + (size_t)BN * MM_BLOCKS;        // BN*MM_BLOCKS
    int*   ws_idx  = (int*)(pmax + (size_t)BN * MM_BLOCKS);// BN*KC
    float* ws_val  = (float*)(ws_idx + (size_t)BN * KC);   // BN*KC

    const int nMega = BN + ORI_MEGA + BN * MM_BLOCKS;      // 2480
    const int nFG   = GAT_BLOCKS + FIN_BLOCKS;             // 13600

    k_clean<<<BN * 10, 512, 0, stream>>>(seg, cleaned);
    k_mega<<<nMega, 512, 0, stream>>>(mscore, cleaned, ori, enh,
                                      ori_idx, pmin, pmax, ws_idx, ws_val);
    k_fg<<<nFG, 256, 0, stream>>>(enh, cleaned, ori_idx, pmin, pmax,
                                  mori, mxo, myo, ws_idx, ws_val, out);
    k_nms<<<BN, 64, 0, stream>>>(out);
}